// Round 3
// baseline (270.928 us; speedup 1.0000x reference)
//
#include <hip/hip_runtime.h>
#include <math.h>

#define B     4096
#define ND    13
#define NS    26
#define NF    39
#define VOCAB 100000
#define NP    351      // number of l<=m pairs in 26x26
#define RPB   8        // rows per block in k_main

// ---------------- workspace layout (floats) ----------------
#define OFF_V    0        // 3328   v[i*26+j] = sum_o clw[128+o] W1[o,i,j]
#define OFF_W0S  3328     // 128*351 W0s[i][p'] = W0[i,l,m] + (l!=m) W0[i,m,l]
#define OFF_A1S  48256    // 351    symmetric-folded A1
#define OFF_GS   48607    // 26*351 Gs[j][p'] = sum_i v[i,j] W0s[i,p']
#define OFF_C2J  57733    // 26
#define OFF_CST  57759    // 1
#define OFF_LUT  57760    // 351 ints: (l<<5)|m
// total ~58111 floats = 232 KB

// ---- precompute stage 1: W0s, A1s+lut, v, cst (all independent) ----
__global__ __launch_bounds__(256) void k_pre1(const float* __restrict__ W0,
                                              const float* __restrict__ W1,
                                              const float* __restrict__ b0,
                                              const float* __restrict__ b1,
                                              const float* __restrict__ clw,
                                              float* __restrict__ W0s,
                                              float* __restrict__ A1s,
                                              float* __restrict__ v,
                                              float* __restrict__ cst,
                                              int* __restrict__ lut) {
    int t = blockIdx.x * 256 + threadIdx.x;
    if (t < 128 * NP) {
        int i = t / NP, p = t - i * NP;
        int l = 0, rem = p;
        while (rem >= NS - l) { rem -= NS - l; l++; }
        int m = l + rem;
        float a = W0[i * 676 + l * 26 + m];
        if (l != m) a += W0[i * 676 + m * 26 + l];
        W0s[t] = a;
    } else if (t < 128 * NP + NP) {
        int p = t - 128 * NP;
        int l = 0, rem = p;
        while (rem >= NS - l) { rem -= NS - l; l++; }
        int m = l + rem;
        float acc = 0.f;
        for (int o = 0; o < 128; o++) {
            float a = W0[o * 676 + l * 26 + m];
            if (l != m) a += W0[o * 676 + m * 26 + l];
            acc += clw[o] * a;
        }
        A1s[p] = acc;
        lut[p] = (l << 5) | m;
    } else if (t < 128 * NP + NP + 3328) {
        int q = t - (128 * NP + NP);
        float acc = 0.f;
        for (int o = 0; o < 128; o++) acc += clw[128 + o] * W1[o * 3328 + q];
        v[q] = acc;
    } else if (t == 128 * NP + NP + 3328) {
        float c = 0.f;
        for (int o = 0; o < 128; o++) c += clw[o] * b0[o] + clw[128 + o] * b1[o];
        cst[0] = 8.f * c;
    }
}

// ---- precompute stage 2: Gs = v^T-contract of W0s, c2j ----
__global__ __launch_bounds__(256) void k_pre2(const float* __restrict__ W0s,
                                              const float* __restrict__ v,
                                              const float* __restrict__ b0,
                                              float* __restrict__ Gs,
                                              float* __restrict__ c2j) {
    int t = blockIdx.x * 256 + threadIdx.x;
    if (t < 26 * NP) {
        int j = t / NP, p = t - j * NP;
        float acc = 0.f;
        for (int i = 0; i < 128; i++) acc += v[i * 26 + j] * W0s[i * NP + p];
        Gs[t] = acc;
    } else if (t < 26 * NP + 26) {
        int j = t - 26 * NP;
        float acc = 0.f;
        for (int i = 0; i < 128; i++) acc += v[i * 26 + j] * b0[i];
        c2j[j] = acc;
    }
}

// ---- fully fused main kernel: gather + linear + CIN + DNN, 8 rows/block ----
__global__ __launch_bounds__(384, 3) void k_main(
    const float* __restrict__ inputs, const float* __restrict__ tables,
    const float* __restrict__ lW, const float* __restrict__ lb,
    const float* __restrict__ Gs, const float* __restrict__ A1s,
    const int* __restrict__ lut, const float* __restrict__ c2j,
    const float* __restrict__ cst,
    const float* __restrict__ dW1, const float* __restrict__ db1,
    const float* __restrict__ dW2, const float* __restrict__ db2,
    const float* __restrict__ dW3, const float* __restrict__ db3,
    const float* __restrict__ dW4, const float* __restrict__ db4,
    const float* __restrict__ clb,
    float* __restrict__ out) {
    __shared__ float insf[RPB][40];       // raw input rows
    __shared__ float xs[RPB][208];        // emb, [r][f*8+k] (CIN layout)
    __shared__ float inT[256][RPB];       // DNN input transposed; reused as partial buf
    __shared__ float h1T[256][RPB];
    __shared__ float h2T[128][RPB];
    __shared__ float h3T[64][RPB];
    __shared__ float lin_s[RPB], scin_s[RPB];
    __shared__ float redbuf[6][RPB];
    float* inF = &inT[0][0];              // flat view, 2048 floats

    int tid = threadIdx.x;
    int b0r = blockIdx.x * RPB;

    // phase 1: stage raw inputs
    for (int t = tid; t < RPB * NF; t += 384) {
        int r = t / NF, c = t - r * NF;
        insf[r][c] = inputs[(b0r + r) * NF + c];
    }
    __syncthreads();

    // phase 2: gather embeddings (both layouts) + dense part of inT + linear term
    for (int t = tid; t < RPB * NS; t += 384) {
        int r = t / NS, f = t - r * NS;
        int idx = (int)insf[r][ND + f];
        const float4* src = (const float4*)(tables + ((long)f * VOCAB + idx) * 8);
        float4 a = src[0], b4 = src[1];
        float4* dst = (float4*)&xs[r][f * 8];
        dst[0] = a; dst[1] = b4;
        int cb = ND + f * 8;
        inT[cb + 0][r] = a.x;  inT[cb + 1][r] = a.y;
        inT[cb + 2][r] = a.z;  inT[cb + 3][r] = a.w;
        inT[cb + 4][r] = b4.x; inT[cb + 5][r] = b4.y;
        inT[cb + 6][r] = b4.z; inT[cb + 7][r] = b4.w;
    }
    for (int t = tid; t < RPB * ND; t += 384) {
        int r = t / ND, c = t - r * ND;
        inT[c][r] = insf[r][c];
    }
    if (tid < RPB) {
        float acc = lb[0];
        for (int c = 0; c < NF; c++) acc += insf[tid][c] * lW[c];
        lin_s[tid] = acc;
    }
    __syncthreads();

    // phase 3: CIN — thread = (l,m) pair, 8 rows amortized per Gs load
    float part[RPB];
    {
        bool act = tid < NP;
        int p = act ? tid : 0;
        int lm = lut[p];
        int l = lm >> 5, m = lm & 31;
        float a1 = A1s[p];
        float acc[RPB][8];
#pragma unroll
        for (int r = 0; r < RPB; r++)
#pragma unroll
            for (int k = 0; k < 8; k++) acc[r][k] = 0.f;
        for (int j = 0; j < NS; j++) {
            float g = Gs[j * NP + p];
#pragma unroll
            for (int r = 0; r < RPB; r++) {
                const float4* xv = (const float4*)&xs[r][j * 8];
                float4 xa = xv[0], xb = xv[1];
                acc[r][0] += g * xa.x; acc[r][1] += g * xa.y;
                acc[r][2] += g * xa.z; acc[r][3] += g * xa.w;
                acc[r][4] += g * xb.x; acc[r][5] += g * xb.y;
                acc[r][6] += g * xb.z; acc[r][7] += g * xb.w;
            }
        }
#pragma unroll
        for (int r = 0; r < RPB; r++) {
            const float4* xlv = (const float4*)&xs[r][l * 8];
            const float4* xmv = (const float4*)&xs[r][m * 8];
            float4 la = xlv[0], lb4 = xlv[1], ma = xmv[0], mb = xmv[1];
            float s;
            s  = (a1 + acc[r][0]) * (la.x * ma.x);
            s += (a1 + acc[r][1]) * (la.y * ma.y);
            s += (a1 + acc[r][2]) * (la.z * ma.z);
            s += (a1 + acc[r][3]) * (la.w * ma.w);
            s += (a1 + acc[r][4]) * (lb4.x * mb.x);
            s += (a1 + acc[r][5]) * (lb4.y * mb.y);
            s += (a1 + acc[r][6]) * (lb4.z * mb.z);
            s += (a1 + acc[r][7]) * (lb4.w * mb.w);
            part[r] = act ? s : 0.f;
        }
    }
#pragma unroll
    for (int off = 1; off < 64; off <<= 1)
#pragma unroll
        for (int r = 0; r < RPB; r++) part[r] += __shfl_xor(part[r], off, 64);
    if ((tid & 63) == 0) {
        int w = tid >> 6;
#pragma unroll
        for (int r = 0; r < RPB; r++) redbuf[w][r] = part[r];
    }
    __syncthreads();

    // phase 4: finalize scin (wave0 low lanes) + DNN layer1 (221 -> 256)
    if (tid < RPB) {
        float s = cst[0];
        for (int w = 0; w < 6; w++) s += redbuf[w][tid];
        float t2 = 0.f;
        for (int j = 0; j < NS; j++) {
            float u = 0.f;
#pragma unroll
            for (int k = 0; k < 8; k++) u += xs[tid][j * 8 + k];
            t2 += c2j[j] * u;
        }
        scin_s[tid] = s + t2;
    }
    if (tid < 256) {
        int o = tid;
        float bias = db1[o];
        float a[RPB];
#pragma unroll
        for (int r = 0; r < RPB; r++) a[r] = bias;
        for (int c = 0; c < 221; c++) {
            float w = dW1[c * 256 + o];
            const float4* iv = (const float4*)&inT[c][0];
            float4 i0 = iv[0], i1 = iv[1];
            a[0] += i0.x * w; a[1] += i0.y * w; a[2] += i0.z * w; a[3] += i0.w * w;
            a[4] += i1.x * w; a[5] += i1.y * w; a[6] += i1.z * w; a[7] += i1.w * w;
        }
        float4 o0, o1;
        o0.x = fmaxf(a[0], 0.f); o0.y = fmaxf(a[1], 0.f);
        o0.z = fmaxf(a[2], 0.f); o0.w = fmaxf(a[3], 0.f);
        o1.x = fmaxf(a[4], 0.f); o1.y = fmaxf(a[5], 0.f);
        o1.z = fmaxf(a[6], 0.f); o1.w = fmaxf(a[7], 0.f);
        float4* hv = (float4*)&h1T[o][0];
        hv[0] = o0; hv[1] = o1;
    }
    __syncthreads();

    // phase 5: DNN layer2 (256 -> 128), split-K over 2 groups
    if (tid < 256) {
        int o = tid & 127, cg = tid >> 7;
        float bias = (cg == 0) ? db2[o] : 0.f;
        float a[RPB];
#pragma unroll
        for (int r = 0; r < RPB; r++) a[r] = bias;
        for (int c = cg * 128; c < cg * 128 + 128; c++) {
            float w = dW2[c * 128 + o];
            const float4* iv = (const float4*)&h1T[c][0];
            float4 i0 = iv[0], i1 = iv[1];
            a[0] += i0.x * w; a[1] += i0.y * w; a[2] += i0.z * w; a[3] += i0.w * w;
            a[4] += i1.x * w; a[5] += i1.y * w; a[6] += i1.z * w; a[7] += i1.w * w;
        }
        float4* pv = (float4*)&inF[tid * 8];
        pv[0] = make_float4(a[0], a[1], a[2], a[3]);
        pv[1] = make_float4(a[4], a[5], a[6], a[7]);
    }
    __syncthreads();
    if (tid < 128) {
        const float4* p0 = (const float4*)&inF[tid * 8];
        const float4* p1 = (const float4*)&inF[(tid + 128) * 8];
        float4 a0 = p0[0], a1 = p0[1], b0v = p1[0], b1v = p1[1];
        float4 o0, o1;
        o0.x = fmaxf(a0.x + b0v.x, 0.f); o0.y = fmaxf(a0.y + b0v.y, 0.f);
        o0.z = fmaxf(a0.z + b0v.z, 0.f); o0.w = fmaxf(a0.w + b0v.w, 0.f);
        o1.x = fmaxf(a1.x + b1v.x, 0.f); o1.y = fmaxf(a1.y + b1v.y, 0.f);
        o1.z = fmaxf(a1.z + b1v.z, 0.f); o1.w = fmaxf(a1.w + b1v.w, 0.f);
        float4* hv = (float4*)&h2T[tid][0];
        hv[0] = o0; hv[1] = o1;
    }
    __syncthreads();

    // phase 6: DNN layer3 (128 -> 64), split-K over 4 groups
    if (tid < 256) {
        int o = tid & 63, cg = tid >> 6;
        float bias = (cg == 0) ? db3[o] : 0.f;
        float a[RPB];
#pragma unroll
        for (int r = 0; r < RPB; r++) a[r] = bias;
        for (int c = cg * 32; c < cg * 32 + 32; c++) {
            float w = dW3[c * 64 + o];
            const float4* iv = (const float4*)&h2T[c][0];
            float4 i0 = iv[0], i1 = iv[1];
            a[0] += i0.x * w; a[1] += i0.y * w; a[2] += i0.z * w; a[3] += i0.w * w;
            a[4] += i1.x * w; a[5] += i1.y * w; a[6] += i1.z * w; a[7] += i1.w * w;
        }
        float4* pv = (float4*)&inF[tid * 8];
        pv[0] = make_float4(a[0], a[1], a[2], a[3]);
        pv[1] = make_float4(a[4], a[5], a[6], a[7]);
    }
    __syncthreads();
    if (tid < 64) {
        float s[RPB];
#pragma unroll
        for (int r = 0; r < RPB; r++) s[r] = 0.f;
#pragma unroll
        for (int cg = 0; cg < 4; cg++) {
            const float4* pv = (const float4*)&inF[(cg * 64 + tid) * 8];
            float4 p0 = pv[0], p1 = pv[1];
            s[0] += p0.x; s[1] += p0.y; s[2] += p0.z; s[3] += p0.w;
            s[4] += p1.x; s[5] += p1.y; s[6] += p1.z; s[7] += p1.w;
        }
        float4 o0, o1;
        o0.x = fmaxf(s[0], 0.f); o0.y = fmaxf(s[1], 0.f);
        o0.z = fmaxf(s[2], 0.f); o0.w = fmaxf(s[3], 0.f);
        o1.x = fmaxf(s[4], 0.f); o1.y = fmaxf(s[5], 0.f);
        o1.z = fmaxf(s[6], 0.f); o1.w = fmaxf(s[7], 0.f);
        float4* hv = (float4*)&h3T[tid][0];
        hv[0] = o0; hv[1] = o1;
    }
    __syncthreads();

    // phase 7: layer4 (64 -> 1) + combine + sigmoid, wave0 only
    if (tid < 64) {
        float w4 = dW4[tid];
        const float4* hv = (const float4*)&h3T[tid][0];
        float4 v0 = hv[0], v1 = hv[1];
        float s[RPB] = { v0.x * w4, v0.y * w4, v0.z * w4, v0.w * w4,
                         v1.x * w4, v1.y * w4, v1.z * w4, v1.w * w4 };
#pragma unroll
        for (int off = 1; off < 64; off <<= 1)
#pragma unroll
            for (int r = 0; r < RPB; r++) s[r] += __shfl_xor(s[r], off, 64);
        if (tid < RPB) {
            float dense = fmaxf(s[tid] + db4[0], 0.f);
            float cin = fmaxf(scin_s[tid] + clb[0], 0.f);
            float x = lin_s[tid] + cin + dense;
            out[b0r + tid] = 1.f / (1.f + expf(-x));
        }
    }
}

extern "C" void kernel_launch(void* const* d_in, const int* in_sizes, int n_in,
                              void* d_out, int out_size, void* d_ws, size_t ws_size,
                              hipStream_t stream) {
    const float* inputs = (const float*)d_in[0];
    const float* tables = (const float*)d_in[1];
    const float* lW     = (const float*)d_in[2];
    const float* lb     = (const float*)d_in[3];
    const float* W0     = (const float*)d_in[4];
    const float* b0     = (const float*)d_in[5];
    const float* W1c    = (const float*)d_in[6];
    const float* b1c    = (const float*)d_in[7];
    const float* clw    = (const float*)d_in[8];
    const float* clb    = (const float*)d_in[9];
    const float* dW1    = (const float*)d_in[10];
    const float* db1    = (const float*)d_in[11];
    const float* dW2    = (const float*)d_in[12];
    const float* db2    = (const float*)d_in[13];
    const float* dW3    = (const float*)d_in[14];
    const float* db3    = (const float*)d_in[15];
    const float* dW4    = (const float*)d_in[16];
    const float* db4    = (const float*)d_in[17];

    float* ws   = (float*)d_ws;
    float* v    = ws + OFF_V;
    float* W0s  = ws + OFF_W0S;
    float* A1s  = ws + OFF_A1S;
    float* Gs   = ws + OFF_GS;
    float* c2j  = ws + OFF_C2J;
    float* cst  = ws + OFF_CST;
    int*   lut  = (int*)(ws + OFF_LUT);

    k_pre1<<<190, 256, 0, stream>>>(W0, W1c, b0, b1c, clw, W0s, A1s, v, cst, lut);
    k_pre2<<<36, 256, 0, stream>>>(W0s, v, b0, Gs, c2j);
    k_main<<<B / RPB, 384, 0, stream>>>(inputs, tables, lW, lb, Gs, A1s, lut, c2j, cst,
                                        dW1, db1, dW2, db2, dW3, db3, dW4, db4, clb,
                                        (float*)d_out);
}